// Round 1
// baseline (3481.174 us; speedup 1.0000x reference)
//
#include <hip/hip_runtime.h>
#include <cstdint>

#define S_LEN 2048
#define EMB   2048
#define NHEAD 16
#define HDIM  128

// ---------------------------------------------------------------------------
// Kernel 1: reduce W1 [2048][1024] over the G=4 group heads into
// Wkv [2048][256]: cols 0..127 = sum_g W1[:, g*128+c] (K weights),
//                  cols 128..255 = sum_g W1[:, 512+g*128+c] (V weights).
// ---------------------------------------------------------------------------
__global__ __launch_bounds__(256) void reduce_w1_kernel(
    const float* __restrict__ W1, float* __restrict__ Wkv) {
  int idx = blockIdx.x * 256 + threadIdx.x;   // 2048*256 total
  int i = idx >> 8;                           // input-feature row
  int c = idx & 255;
  int base = (c < 128) ? c : (c + 384);       // v: 512 + (c-128) = c + 384
  const float* r = W1 + (size_t)i * 1024 + base;
  Wkv[idx] = (r[0] + r[128]) + (r[256] + r[384]);
}

// ---------------------------------------------------------------------------
// Kernel 2: fp32 GEMM C[M,N] = A[M,K] @ B[K,N], all row-major.
// 64x64 block tile, 256 threads, 4x4 microtile, K-chunk 16.
// All dims here are multiples of 64 (N=256 or 2048), K mult of 16.
// ---------------------------------------------------------------------------
__global__ __launch_bounds__(256) void gemm_f32(
    const float* __restrict__ A, const float* __restrict__ B,
    float* __restrict__ C, int M, int N, int K) {
  __shared__ float As[16][68];   // stored transposed: As[k][row]; pad->16B align
  __shared__ float Bs[16][68];
  const int tid = threadIdx.x;
  const int tx = tid & 15, ty = tid >> 4;
  const int row0 = blockIdx.y * 64, col0 = blockIdx.x * 64;
  float acc[4][4] = {};

  for (int k0 = 0; k0 < K; k0 += 16) {
    {   // A tile: 64 rows x 16 k — one float4 per thread
      int r = tid >> 2;
      int c = (tid & 3) * 4;
      float4 a4 = *(const float4*)(A + (size_t)(row0 + r) * K + k0 + c);
      As[c + 0][r] = a4.x; As[c + 1][r] = a4.y;
      As[c + 2][r] = a4.z; As[c + 3][r] = a4.w;
    }
    {   // B tile: 16 k x 64 cols — one float4 per thread
      int r = tid >> 4;
      int c = (tid & 15) * 4;
      *(float4*)&Bs[r][c] = *(const float4*)(B + (size_t)(k0 + r) * N + col0 + c);
    }
    __syncthreads();
#pragma unroll
    for (int kk = 0; kk < 16; ++kk) {
      float4 a = *(const float4*)&As[kk][ty * 4];
      float4 b = *(const float4*)&Bs[kk][tx * 4];
      float av[4] = {a.x, a.y, a.z, a.w};
      float bv[4] = {b.x, b.y, b.z, b.w};
#pragma unroll
      for (int i = 0; i < 4; ++i)
#pragma unroll
        for (int j = 0; j < 4; ++j)
          acc[i][j] = fmaf(av[i], bv[j], acc[i][j]);
    }
    __syncthreads();
  }
#pragma unroll
  for (int i = 0; i < 4; ++i) {
    float4 v = make_float4(acc[i][0], acc[i][1], acc[i][2], acc[i][3]);
    *(float4*)(C + (size_t)(row0 + ty * 4 + i) * N + col0 + tx * 4) = v;
  }
}

// ---------------------------------------------------------------------------
// Kernel 3: flash-style attention, fp32, online softmax.
// Q  [B*S][EMB]  (col h*128+e), KV [B*S][256] (k: 0..127, v: 128..255),
// mask [B][S][S], AO [B*S][EMB] (col h*128+e).
// Block: 256 threads, BM=32 Q-rows, BN=32 keys per iteration.
// grid = (S/32, B*H)
// ---------------------------------------------------------------------------
__global__ __launch_bounds__(256) void flash_kernel(
    const float* __restrict__ Q, const float* __restrict__ KV,
    const float* __restrict__ mask, float* __restrict__ AO) {
  __shared__ float Qs[32][132];   // +4 pad: 16B-aligned rows, 4-bank row shift
  __shared__ float Ks[32][132];
  __shared__ float Vs[32][132];
  __shared__ float Ss[32][33];
  __shared__ float mrow[32], lrow[32], arow[32];

  const int tid = threadIdx.x;
  const int bh  = blockIdx.y;          // 0..31
  const int b   = bh >> 4;
  const int h   = bh & 15;
  const int t0  = blockIdx.x * 32;

  // ---- load Q tile [32][128]
  {
    int r  = tid >> 3;
    int c0 = (tid & 7) * 16;
    const float* src = Q + (size_t)(b * S_LEN + t0 + r) * EMB + h * HDIM + c0;
#pragma unroll
    for (int j = 0; j < 4; ++j)
      *(float4*)&Qs[r][c0 + 4 * j] = ((const float4*)src)[j];
  }
  if (tid < 32) { mrow[tid] = -3.0e38f; lrow[tid] = 0.f; }

  const int r_o = tid >> 3;            // O-accumulator: row, 16 cols per thread
  const int c_o = (tid & 7) * 16;
  float Oacc[16];
#pragma unroll
  for (int j = 0; j < 16; ++j) Oacc[j] = 0.f;

  for (int s0 = 0; s0 < S_LEN; s0 += 32) {
    __syncthreads();                   // previous iter done with Ks/Vs/Ss
    {   // ---- load K/V tiles [32][128] each
      int r  = tid >> 3;
      int c0 = (tid & 7) * 16;
      const float* kvp = KV + (size_t)(b * S_LEN + s0 + r) * 256;
#pragma unroll
      for (int j = 0; j < 4; ++j) {
        *(float4*)&Ks[r][c0 + 4 * j] = ((const float4*)(kvp + c0))[j];
        *(float4*)&Vs[r][c0 + 4 * j] = ((const float4*)(kvp + 128 + c0))[j];
      }
    }
    __syncthreads();
    {   // ---- scores: each thread 4 rows x 1 key col
      int sc = tid & 31;
      int r0 = (tid >> 5) * 4;
      float a0 = 0.f, a1 = 0.f, a2 = 0.f, a3 = 0.f;
#pragma unroll 4
      for (int e = 0; e < 128; e += 4) {
        float4 kk = *(const float4*)&Ks[sc][e];
        float4 q0 = *(const float4*)&Qs[r0 + 0][e];
        float4 q1 = *(const float4*)&Qs[r0 + 1][e];
        float4 q2 = *(const float4*)&Qs[r0 + 2][e];
        float4 q3 = *(const float4*)&Qs[r0 + 3][e];
        a0 += q0.x * kk.x + q0.y * kk.y + q0.z * kk.z + q0.w * kk.w;
        a1 += q1.x * kk.x + q1.y * kk.y + q1.z * kk.z + q1.w * kk.w;
        a2 += q2.x * kk.x + q2.y * kk.y + q2.z * kk.z + q2.w * kk.w;
        a3 += q3.x * kk.x + q3.y * kk.y + q3.z * kk.z + q3.w * kk.w;
      }
      const float* mp = mask + (size_t)b * S_LEN * S_LEN
                             + (size_t)t0 * S_LEN + (s0 + sc);
      Ss[r0 + 0][sc] = a0 + mp[(size_t)(r0 + 0) * S_LEN];
      Ss[r0 + 1][sc] = a1 + mp[(size_t)(r0 + 1) * S_LEN];
      Ss[r0 + 2][sc] = a2 + mp[(size_t)(r0 + 2) * S_LEN];
      Ss[r0 + 3][sc] = a3 + mp[(size_t)(r0 + 3) * S_LEN];
    }
    __syncthreads();
    if (tid < 32) {   // ---- online softmax bookkeeping, one thread per row
      int r = tid;
      float mx = mrow[r];
#pragma unroll
      for (int s = 0; s < 32; ++s) mx = fmaxf(mx, Ss[r][s]);
      float a = __expf(mrow[r] - mx);
      float sum = 0.f;
#pragma unroll
      for (int s = 0; s < 32; ++s) {
        float p = __expf(Ss[r][s] - mx);
        Ss[r][s] = p;
        sum += p;
      }
      lrow[r] = lrow[r] * a + sum;
      mrow[r] = mx;
      arow[r] = a;
    }
    __syncthreads();
    {   // ---- O = O*alpha + P @ V
      float a = arow[r_o];
#pragma unroll
      for (int j = 0; j < 16; ++j) Oacc[j] *= a;
      for (int s = 0; s < 32; ++s) {
        float p = Ss[r_o][s];
        float4 v0 = *(const float4*)&Vs[s][c_o + 0];
        float4 v1 = *(const float4*)&Vs[s][c_o + 4];
        float4 v2 = *(const float4*)&Vs[s][c_o + 8];
        float4 v3 = *(const float4*)&Vs[s][c_o + 12];
        Oacc[0]  = fmaf(p, v0.x, Oacc[0]);  Oacc[1]  = fmaf(p, v0.y, Oacc[1]);
        Oacc[2]  = fmaf(p, v0.z, Oacc[2]);  Oacc[3]  = fmaf(p, v0.w, Oacc[3]);
        Oacc[4]  = fmaf(p, v1.x, Oacc[4]);  Oacc[5]  = fmaf(p, v1.y, Oacc[5]);
        Oacc[6]  = fmaf(p, v1.z, Oacc[6]);  Oacc[7]  = fmaf(p, v1.w, Oacc[7]);
        Oacc[8]  = fmaf(p, v2.x, Oacc[8]);  Oacc[9]  = fmaf(p, v2.y, Oacc[9]);
        Oacc[10] = fmaf(p, v2.z, Oacc[10]); Oacc[11] = fmaf(p, v2.w, Oacc[11]);
        Oacc[12] = fmaf(p, v3.x, Oacc[12]); Oacc[13] = fmaf(p, v3.y, Oacc[13]);
        Oacc[14] = fmaf(p, v3.z, Oacc[14]); Oacc[15] = fmaf(p, v3.w, Oacc[15]);
      }
    }
  }
  // ---- normalize + store
  float inv_l = 1.0f / lrow[r_o];
  float* dst = AO + (size_t)(b * S_LEN + t0 + r_o) * EMB + h * HDIM + c_o;
#pragma unroll
  for (int j = 0; j < 4; ++j) {
    float4 v = make_float4(Oacc[4 * j + 0] * inv_l, Oacc[4 * j + 1] * inv_l,
                           Oacc[4 * j + 2] * inv_l, Oacc[4 * j + 3] * inv_l);
    ((float4*)dst)[j] = v;
  }
}

// ---------------------------------------------------------------------------
extern "C" void kernel_launch(void* const* d_in, const int* in_sizes, int n_in,
                              void* d_out, int out_size, void* d_ws, size_t ws_size,
                              hipStream_t stream) {
  const float* x    = (const float*)d_in[0];   // [B,S,E]
  const float* mask = (const float*)d_in[1];   // [B,1,S,S]
  const float* W1   = (const float*)d_in[2];   // [E,1024]
  const float* W2   = (const float*)d_in[3];   // [E,E]
  const float* W3   = (const float*)d_in[4];   // [E,E]
  float* out = (float*)d_out;                  // [B,S,E]

  char* ws = (char*)d_ws;
  float* Q   = (float*)(ws);                                  // 4096*2048 f32 = 32 MiB
  float* KV  = (float*)(ws + 33554432);                       // 4096*256  f32 =  4 MiB
  float* Wkv = (float*)(ws + 33554432 + 4194304);             // 2048*256  f32 =  2 MiB
  float* AO  = (float*)(ws + 33554432 + 4194304 + 2097152);   // 4096*2048 f32 = 32 MiB

  const int M = 2 * S_LEN;   // 4096

  // 1) W1 group-reduction -> Wkv [2048][256]
  reduce_w1_kernel<<<2048, 256, 0, stream>>>(W1, Wkv);
  // 2) Q = x @ W2   [4096][2048]
  gemm_f32<<<dim3(EMB / 64, M / 64), 256, 0, stream>>>(x, W2, Q, M, EMB, EMB);
  // 3) KV = x @ Wkv [4096][256]
  gemm_f32<<<dim3(256 / 64, M / 64), 256, 0, stream>>>(x, Wkv, KV, M, 256, EMB);
  // 4) attention -> AO [4096][2048]
  flash_kernel<<<dim3(S_LEN / 32, 2 * NHEAD), 256, 0, stream>>>(Q, KV, mask, AO);
  // 5) out = AO @ W3
  gemm_f32<<<dim3(EMB / 64, M / 64), 256, 0, stream>>>(AO, W3, out, M, EMB, EMB);
}

// Round 2
// 1358.961 us; speedup vs baseline: 2.5616x; 2.5616x over previous
//
#include <hip/hip_runtime.h>
#include <cstdint>

#define S_LEN 2048
#define EMB   2048
#define NHEAD 16
#define HDIM  128

typedef __attribute__((ext_vector_type(8))) short short8;
typedef __attribute__((ext_vector_type(4))) short short4v;
typedef __attribute__((ext_vector_type(4))) float f32x4;

// round-to-nearest-even float -> bf16 (finite inputs)
__device__ inline short f2bf(float x) {
  union { float f; uint32_t u; } v; v.f = x;
  uint32_t r = v.u + 0x7fffu + ((v.u >> 16) & 1u);
  return (short)(r >> 16);
}
__device__ inline float bf2f(short b) {
  union { uint32_t u; float f; } v; v.u = ((uint32_t)(uint16_t)b) << 16;
  return v.f;
}

// ---------------------------------------------------------------------------
// Kernel 1: reduce W1 over G=4 heads -> Wkv [2048][256] (k cols 0..127, v 128..255)
// ---------------------------------------------------------------------------
__global__ __launch_bounds__(256) void reduce_w1_kernel(
    const float* __restrict__ W1, float* __restrict__ Wkv) {
  int idx = blockIdx.x * 256 + threadIdx.x;
  int i = idx >> 8;
  int c = idx & 255;
  int base = (c < 128) ? c : (c + 384);
  const float* r = W1 + (size_t)i * 1024 + base;
  Wkv[idx] = (r[0] + r[128]) + (r[256] + r[384]);
}

// ---------------------------------------------------------------------------
// Kernel 2: fp32 GEMM C = A@B (row-major), 64x64 tile, 4x4 microtile.
// ---------------------------------------------------------------------------
__global__ __launch_bounds__(256) void gemm_f32(
    const float* __restrict__ A, const float* __restrict__ B,
    float* __restrict__ C, int M, int N, int K) {
  __shared__ float As[16][68];
  __shared__ float Bs[16][68];
  const int tid = threadIdx.x;
  const int tx = tid & 15, ty = tid >> 4;
  const int row0 = blockIdx.y * 64, col0 = blockIdx.x * 64;
  float acc[4][4] = {};
  for (int k0 = 0; k0 < K; k0 += 16) {
    {
      int r = tid >> 2;
      int c = (tid & 3) * 4;
      float4 a4 = *(const float4*)(A + (size_t)(row0 + r) * K + k0 + c);
      As[c + 0][r] = a4.x; As[c + 1][r] = a4.y;
      As[c + 2][r] = a4.z; As[c + 3][r] = a4.w;
    }
    {
      int r = tid >> 4;
      int c = (tid & 15) * 4;
      *(float4*)&Bs[r][c] = *(const float4*)(B + (size_t)(k0 + r) * N + col0 + c);
    }
    __syncthreads();
#pragma unroll
    for (int kk = 0; kk < 16; ++kk) {
      float4 a = *(const float4*)&As[kk][ty * 4];
      float4 b = *(const float4*)&Bs[kk][tx * 4];
      float av[4] = {a.x, a.y, a.z, a.w};
      float bv[4] = {b.x, b.y, b.z, b.w};
#pragma unroll
      for (int i = 0; i < 4; ++i)
#pragma unroll
        for (int j = 0; j < 4; ++j)
          acc[i][j] = fmaf(av[i], bv[j], acc[i][j]);
    }
    __syncthreads();
  }
#pragma unroll
  for (int i = 0; i < 4; ++i) {
    float4 v = make_float4(acc[i][0], acc[i][1], acc[i][2], acc[i][3]);
    *(float4*)(C + (size_t)(row0 + ty * 4 + i) * N + col0 + tx * 4) = v;
  }
}

// ---------------------------------------------------------------------------
// Kernel 2b: same GEMM but epilogue stores split-bf16 (hi + lo) instead of f32.
// ---------------------------------------------------------------------------
__global__ __launch_bounds__(256) void gemm_f32_split(
    const float* __restrict__ A, const float* __restrict__ B,
    short* __restrict__ Chi, short* __restrict__ Clo, int M, int N, int K) {
  __shared__ float As[16][68];
  __shared__ float Bs[16][68];
  const int tid = threadIdx.x;
  const int tx = tid & 15, ty = tid >> 4;
  const int row0 = blockIdx.y * 64, col0 = blockIdx.x * 64;
  float acc[4][4] = {};
  for (int k0 = 0; k0 < K; k0 += 16) {
    {
      int r = tid >> 2;
      int c = (tid & 3) * 4;
      float4 a4 = *(const float4*)(A + (size_t)(row0 + r) * K + k0 + c);
      As[c + 0][r] = a4.x; As[c + 1][r] = a4.y;
      As[c + 2][r] = a4.z; As[c + 3][r] = a4.w;
    }
    {
      int r = tid >> 4;
      int c = (tid & 15) * 4;
      *(float4*)&Bs[r][c] = *(const float4*)(B + (size_t)(k0 + r) * N + col0 + c);
    }
    __syncthreads();
#pragma unroll
    for (int kk = 0; kk < 16; ++kk) {
      float4 a = *(const float4*)&As[kk][ty * 4];
      float4 b = *(const float4*)&Bs[kk][tx * 4];
      float av[4] = {a.x, a.y, a.z, a.w};
      float bv[4] = {b.x, b.y, b.z, b.w};
#pragma unroll
      for (int i = 0; i < 4; ++i)
#pragma unroll
        for (int j = 0; j < 4; ++j)
          acc[i][j] = fmaf(av[i], bv[j], acc[i][j]);
    }
    __syncthreads();
  }
#pragma unroll
  for (int i = 0; i < 4; ++i) {
    short4v hi, lo;
#pragma unroll
    for (int j = 0; j < 4; ++j) {
      float v = acc[i][j];
      short h = f2bf(v);
      hi[j] = h;
      lo[j] = f2bf(v - bf2f(h));
    }
    size_t off = (size_t)(row0 + ty * 4 + i) * N + col0 + tx * 4;
    *(short4v*)(Chi + off) = hi;
    *(short4v*)(Clo + off) = lo;
  }
}

// ---------------------------------------------------------------------------
// Kernel 3: split KV f32 [4096][256] -> Kh,Kl bf16 [4096][128], VT bf16 [2][128][2048]
// ---------------------------------------------------------------------------
__global__ __launch_bounds__(256) void split_kv_kernel(
    const float* __restrict__ KV, short* __restrict__ Kh,
    short* __restrict__ Kl, short* __restrict__ VT) {
  int idx = blockIdx.x * 256 + threadIdx.x;   // 262144 total
  if (idx < 131072) {                          // K path: 4096 rows x 128/4
    int row = idx >> 5;
    int c4 = (idx & 31) * 4;
    float4 v = *(const float4*)(KV + (size_t)row * 256 + c4);
    float vv[4] = {v.x, v.y, v.z, v.w};
    short4v hi, lo;
#pragma unroll
    for (int j = 0; j < 4; ++j) {
      short h = f2bf(vv[j]);
      hi[j] = h;
      lo[j] = f2bf(vv[j] - bf2f(h));
    }
    *(short4v*)(Kh + (size_t)row * 128 + c4) = hi;
    *(short4v*)(Kl + (size_t)row * 128 + c4) = lo;
  } else {                                     // V path -> transposed bf16
    int j = idx - 131072;                      // 131072 = 1024 s4 * 128 d
    int d = j & 127;
    int s4 = (j >> 7) * 4;
    int b = s4 >> 11;
    int s = s4 & 2047;
    short4v o;
#pragma unroll
    for (int i = 0; i < 4; ++i)
      o[i] = f2bf(KV[(size_t)(b * S_LEN + s + i) * 256 + 128 + d]);
    *(short4v*)(VT + ((size_t)(b * HDIM + d)) * S_LEN + s) = o;
  }
}

// ---------------------------------------------------------------------------
// Kernel 4: MFMA flash attention.
// Qh/Ql [4096][2048] bf16 (col h*128+e), Kh/Kl [4096][128] bf16,
// VT [2][128][2048] bf16, mask [2][2048][2048] f32, AO [4096][2048] f32.
// grid (S/64, B*H), 256 threads = 4 waves; wave w owns Q-rows 16w..16w+15.
// ---------------------------------------------------------------------------
#define LDK 136   // shorts per K/Q LDS row   (272 B, 16B-aligned, 2-way free)
#define LDV 80    // shorts per VT LDS row    (160 B)
#define LDP 72    // shorts per P LDS row     (144 B)

__global__ __launch_bounds__(256, 2) void flash_mfma(
    const short* __restrict__ Qh, const short* __restrict__ Ql,
    const short* __restrict__ Kh, const short* __restrict__ Kl,
    const short* __restrict__ VT, const float* __restrict__ mask,
    float* __restrict__ AO) {
  __shared__ short KhS[64 * LDK];
  __shared__ short KlS[64 * LDK];
  __shared__ short VtS[128 * LDV];
  __shared__ short PsS[4][16 * LDP];

  const int tid   = threadIdx.x;
  const int w     = tid >> 6;
  const int lane  = tid & 63;
  const int quad  = lane >> 4;
  const int col16 = lane & 15;
  const int bh = blockIdx.y, b = bh >> 4, h = bh & 15;
  const int t0 = blockIdx.x * 64;

  // ---- stage Q tile (reusing KhS/KlS), then pull A-fragments to registers
  {
    int r = tid >> 2, c0 = (tid & 3) * 32;
    const short* qh = Qh + (size_t)(b * S_LEN + t0 + r) * EMB + h * HDIM + c0;
    const short* ql = Ql + (size_t)(b * S_LEN + t0 + r) * EMB + h * HDIM + c0;
#pragma unroll
    for (int j = 0; j < 4; ++j) {
      *(short8*)&KhS[r * LDK + c0 + 8 * j] = *(const short8*)(qh + 8 * j);
      *(short8*)&KlS[r * LDK + c0 + 8 * j] = *(const short8*)(ql + 8 * j);
    }
  }
  __syncthreads();
  short8 qfh[4], qfl[4];
#pragma unroll
  for (int c = 0; c < 4; ++c) {
    qfh[c] = *(const short8*)&KhS[(16 * w + col16) * LDK + c * 32 + quad * 8];
    qfl[c] = *(const short8*)&KlS[(16 * w + col16) * LDK + c * 32 + quad * 8];
  }

  f32x4 oacc[8];
#pragma unroll
  for (int d = 0; d < 8; ++d) { oacc[d][0] = 0.f; oacc[d][1] = 0.f; oacc[d][2] = 0.f; oacc[d][3] = 0.f; }
  float mrow[4] = {-3.0e38f, -3.0e38f, -3.0e38f, -3.0e38f};
  float lrow[4] = {0.f, 0.f, 0.f, 0.f};

  for (int s0 = 0; s0 < S_LEN; s0 += 64) {
    __syncthreads();   // previous LDS consumers done (incl. Q-frag extraction)
    {   // ---- stage K hi/lo [64][128] and V^T [128][64]
      int r = tid >> 2, c0 = (tid & 3) * 32;
      const short* kh = Kh + (size_t)(b * S_LEN + s0 + r) * HDIM + c0;
      const short* kl = Kl + (size_t)(b * S_LEN + s0 + r) * HDIM + c0;
#pragma unroll
      for (int j = 0; j < 4; ++j) {
        *(short8*)&KhS[r * LDK + c0 + 8 * j] = *(const short8*)(kh + 8 * j);
        *(short8*)&KlS[r * LDK + c0 + 8 * j] = *(const short8*)(kl + 8 * j);
      }
      int d = tid >> 1, c1 = (tid & 1) * 32;
      const short* vt = VT + (size_t)(b * HDIM + d) * S_LEN + s0 + c1;
#pragma unroll
      for (int j = 0; j < 4; ++j)
        *(short8*)&VtS[d * LDV + c1 + 8 * j] = *(const short8*)(vt + 8 * j);
    }
    // ---- mask -> registers (C-layout elements)
    float mreg[4][4];
    {
      const float* mp = mask + (size_t)b * S_LEN * S_LEN
                      + (size_t)(t0 + 16 * w + quad * 4) * S_LEN + s0 + col16;
#pragma unroll
      for (int r = 0; r < 4; ++r)
#pragma unroll
        for (int nt = 0; nt < 4; ++nt)
          mreg[r][nt] = mp[(size_t)r * S_LEN + nt * 16];
    }
    __syncthreads();

    // ---- scores: S[16 x 64] per wave, split-bf16 (hi*hi + hi*lo + lo*hi)
    f32x4 sacc[4];
#pragma unroll
    for (int nt = 0; nt < 4; ++nt) { sacc[nt][0] = 0.f; sacc[nt][1] = 0.f; sacc[nt][2] = 0.f; sacc[nt][3] = 0.f; }
#pragma unroll
    for (int c = 0; c < 4; ++c) {
#pragma unroll
      for (int nt = 0; nt < 4; ++nt) {
        const short* kb  = &KhS[(nt * 16 + col16) * LDK + c * 32 + quad * 8];
        const short* klb = &KlS[(nt * 16 + col16) * LDK + c * 32 + quad * 8];
        short8 kh8 = *(const short8*)kb;
        short8 kl8 = *(const short8*)klb;
        sacc[nt] = __builtin_amdgcn_mfma_f32_16x16x32_bf16(qfh[c], kh8, sacc[nt], 0, 0, 0);
        sacc[nt] = __builtin_amdgcn_mfma_f32_16x16x32_bf16(qfl[c], kh8, sacc[nt], 0, 0, 0);
        sacc[nt] = __builtin_amdgcn_mfma_f32_16x16x32_bf16(qfh[c], kl8, sacc[nt], 0, 0, 0);
      }
    }

    // ---- online softmax (rows quad*4+r live in 16 lanes sharing `quad`)
    float alr[4];
#pragma unroll
    for (int r = 0; r < 4; ++r) {
      float v0 = sacc[0][r] + mreg[r][0];
      float v1 = sacc[1][r] + mreg[r][1];
      float v2 = sacc[2][r] + mreg[r][2];
      float v3 = sacc[3][r] + mreg[r][3];
      float mx = fmaxf(fmaxf(v0, v1), fmaxf(v2, v3));
      mx = fmaxf(mx, __shfl_xor(mx, 1));
      mx = fmaxf(mx, __shfl_xor(mx, 2));
      mx = fmaxf(mx, __shfl_xor(mx, 4));
      mx = fmaxf(mx, __shfl_xor(mx, 8));
      float nm = fmaxf(mrow[r], mx);
      short p0 = f2bf(__expf(v0 - nm));
      short p1 = f2bf(__expf(v1 - nm));
      short p2 = f2bf(__expf(v2 - nm));
      short p3 = f2bf(__expf(v3 - nm));
      // sum the ROUNDED p so numerator/denominator rounding cancels
      float ps = (bf2f(p0) + bf2f(p1)) + (bf2f(p2) + bf2f(p3));
      ps += __shfl_xor(ps, 1);
      ps += __shfl_xor(ps, 2);
      ps += __shfl_xor(ps, 4);
      ps += __shfl_xor(ps, 8);
      float al = __expf(mrow[r] - nm);
      lrow[r] = lrow[r] * al + ps;
      mrow[r] = nm;
      alr[r] = al;
      int pbase = (quad * 4 + r) * LDP + col16;
      PsS[w][pbase + 0]  = p0;
      PsS[w][pbase + 16] = p1;
      PsS[w][pbase + 32] = p2;
      PsS[w][pbase + 48] = p3;
    }
    // ---- rescale O
#pragma unroll
    for (int d = 0; d < 8; ++d)
#pragma unroll
      for (int r = 0; r < 4; ++r) oacc[d][r] *= alr[r];

    __asm__ volatile("s_waitcnt lgkmcnt(0)" ::: "memory");  // P visible in-wave

    // ---- O += P @ V
    short8 pa0 = *(const short8*)&PsS[w][col16 * LDP + quad * 8];
    short8 pa1 = *(const short8*)&PsS[w][col16 * LDP + 32 + quad * 8];
#pragma unroll
    for (int d = 0; d < 8; ++d) {
      const short* vb = &VtS[(d * 16 + col16) * LDV + quad * 8];
      short8 vb0 = *(const short8*)(vb);
      short8 vb1 = *(const short8*)(vb + 32);
      oacc[d] = __builtin_amdgcn_mfma_f32_16x16x32_bf16(pa0, vb0, oacc[d], 0, 0, 0);
      oacc[d] = __builtin_amdgcn_mfma_f32_16x16x32_bf16(pa1, vb1, oacc[d], 0, 0, 0);
    }
  }

  // ---- epilogue: normalize rows, store f32
#pragma unroll
  for (int r = 0; r < 4; ++r) {
    float inv = 1.0f / lrow[r];
    float* dst = AO + (size_t)(b * S_LEN + t0 + 16 * w + quad * 4 + r) * EMB
               + h * HDIM + col16;
#pragma unroll
    for (int d = 0; d < 8; ++d) dst[d * 16] = oacc[d][r] * inv;
  }
}

// ---------------------------------------------------------------------------
extern "C" void kernel_launch(void* const* d_in, const int* in_sizes, int n_in,
                              void* d_out, int out_size, void* d_ws, size_t ws_size,
                              hipStream_t stream) {
  const float* x    = (const float*)d_in[0];
  const float* mask = (const float*)d_in[1];
  const float* W1   = (const float*)d_in[2];
  const float* W2   = (const float*)d_in[3];
  const float* W3   = (const float*)d_in[4];
  float* out = (float*)d_out;

  char* ws = (char*)d_ws;
  size_t off = 0;
  float* KV  = (float*)(ws + off); off += (size_t)4096 * 256 * 4;        // 4 MiB
  float* Wkv = (float*)(ws + off); off += (size_t)2048 * 256 * 4;        // 2 MiB
  float* AO  = (float*)(ws + off); off += (size_t)4096 * 2048 * 4;       // 32 MiB
  short* Qh  = (short*)(ws + off); off += (size_t)4096 * 2048 * 2;       // 16 MiB
  short* Ql  = (short*)(ws + off); off += (size_t)4096 * 2048 * 2;       // 16 MiB
  short* Khb = (short*)(ws + off); off += (size_t)4096 * 128 * 2;        // 1 MiB
  short* Klb = (short*)(ws + off); off += (size_t)4096 * 128 * 2;        // 1 MiB
  short* VT  = (short*)(ws + off); off += (size_t)2 * 128 * 2048 * 2;    // 1 MiB

  const int M = 2 * S_LEN;  // 4096

  reduce_w1_kernel<<<2048, 256, 0, stream>>>(W1, Wkv);
  gemm_f32_split<<<dim3(EMB / 64, M / 64), 256, 0, stream>>>(x, W2, Qh, Ql, M, EMB, EMB);
  gemm_f32<<<dim3(256 / 64, M / 64), 256, 0, stream>>>(x, Wkv, KV, M, 256, EMB);
  split_kv_kernel<<<1024, 256, 0, stream>>>(KV, Khb, Klb, VT);
  flash_mfma<<<dim3(S_LEN / 64, 2 * NHEAD), 256, 0, stream>>>(Qh, Ql, Khb, Klb, VT, mask, AO);
  gemm_f32<<<dim3(EMB / 64, M / 64), 256, 0, stream>>>(AO, W3, out, M, EMB, EMB);
}

// Round 3
// 655.674 us; speedup vs baseline: 5.3093x; 2.0726x over previous
//
#include <hip/hip_runtime.h>
#include <cstdint>

#define S_LEN 2048
#define EMB   2048
#define NHEAD 16
#define HDIM  128

typedef __attribute__((ext_vector_type(8))) short short8;
typedef __attribute__((ext_vector_type(4))) short short4v;
typedef __attribute__((ext_vector_type(4))) float f32x4;
typedef unsigned int u32;

// round-to-nearest-even float -> bf16 (finite inputs)
__device__ inline short f2bf(float x) {
  union { float f; uint32_t u; } v; v.f = x;
  uint32_t r = v.u + 0x7fffu + ((v.u >> 16) & 1u);
  return (short)(r >> 16);
}
__device__ inline float bf2f(short b) {
  union { uint32_t u; float f; } v; v.u = ((uint32_t)(uint16_t)b) << 16;
  return v.f;
}

// async global->LDS, 16B per lane; lds base must be wave-uniform
__device__ inline void glds16(const short* g, short* l) {
  __builtin_amdgcn_global_load_lds(
      (const __attribute__((address_space(1))) u32*)g,
      (__attribute__((address_space(3))) u32*)l, 16, 0, 0);
}

// ---------------------------------------------------------------------------
// W1 group-reduce -> Wkv [2048][256] (k cols 0..127, v cols 128..255)
// ---------------------------------------------------------------------------
__global__ __launch_bounds__(256) void reduce_w1_kernel(
    const float* __restrict__ W1, float* __restrict__ Wkv) {
  int idx = blockIdx.x * 256 + threadIdx.x;
  int i = idx >> 8;
  int c = idx & 255;
  int base = (c < 128) ? c : (c + 384);
  const float* r = W1 + (size_t)i * 1024 + base;
  Wkv[idx] = (r[0] + r[128]) + (r[256] + r[384]);
}

// ---------------------------------------------------------------------------
// fp32 GEMM (used only for KV: N=256) — 64x64 tile, 4x4 microtile.
// ---------------------------------------------------------------------------
__global__ __launch_bounds__(256) void gemm_f32(
    const float* __restrict__ A, const float* __restrict__ B,
    float* __restrict__ C, int M, int N, int K) {
  __shared__ float As[16][68];
  __shared__ float Bs[16][68];
  const int tid = threadIdx.x;
  const int tx = tid & 15, ty = tid >> 4;
  const int row0 = blockIdx.y * 64, col0 = blockIdx.x * 64;
  float acc[4][4] = {};
  for (int k0 = 0; k0 < K; k0 += 16) {
    {
      int r = tid >> 2;
      int c = (tid & 3) * 4;
      float4 a4 = *(const float4*)(A + (size_t)(row0 + r) * K + k0 + c);
      As[c + 0][r] = a4.x; As[c + 1][r] = a4.y;
      As[c + 2][r] = a4.z; As[c + 3][r] = a4.w;
    }
    {
      int r = tid >> 4;
      int c = (tid & 15) * 4;
      *(float4*)&Bs[r][c] = *(const float4*)(B + (size_t)(k0 + r) * N + col0 + c);
    }
    __syncthreads();
#pragma unroll
    for (int kk = 0; kk < 16; ++kk) {
      float4 a = *(const float4*)&As[kk][ty * 4];
      float4 b = *(const float4*)&Bs[kk][tx * 4];
      float av[4] = {a.x, a.y, a.z, a.w};
      float bv[4] = {b.x, b.y, b.z, b.w};
#pragma unroll
      for (int i = 0; i < 4; ++i)
#pragma unroll
        for (int j = 0; j < 4; ++j)
          acc[i][j] = fmaf(av[i], bv[j], acc[i][j]);
    }
    __syncthreads();
  }
#pragma unroll
  for (int i = 0; i < 4; ++i) {
    float4 v = make_float4(acc[i][0], acc[i][1], acc[i][2], acc[i][3]);
    *(float4*)(C + (size_t)(row0 + ty * 4 + i) * N + col0 + tx * 4) = v;
  }
}

// ---------------------------------------------------------------------------
// split KV f32 [4096][256] -> Kh,Kl bf16 [4096][128], VT bf16 [2][128][2048]
// ---------------------------------------------------------------------------
__global__ __launch_bounds__(256) void split_kv_kernel(
    const float* __restrict__ KV, short* __restrict__ Kh,
    short* __restrict__ Kl, short* __restrict__ VT) {
  int idx = blockIdx.x * 256 + threadIdx.x;
  if (idx < 131072) {
    int row = idx >> 5;
    int c4 = (idx & 31) * 4;
    float4 v = *(const float4*)(KV + (size_t)row * 256 + c4);
    float vv[4] = {v.x, v.y, v.z, v.w};
    short4v hi, lo;
#pragma unroll
    for (int j = 0; j < 4; ++j) {
      short h = f2bf(vv[j]);
      hi[j] = h;
      lo[j] = f2bf(vv[j] - bf2f(h));
    }
    *(short4v*)(Kh + (size_t)row * 128 + c4) = hi;
    *(short4v*)(Kl + (size_t)row * 128 + c4) = lo;
  } else {
    int j = idx - 131072;
    int d = j & 127;
    int s4 = (j >> 7) * 4;
    int b = s4 >> 11;
    int s = s4 & 2047;
    short4v o;
#pragma unroll
    for (int i = 0; i < 4; ++i)
      o[i] = f2bf(KV[(size_t)(b * S_LEN + s + i) * 256 + 128 + d]);
    *(short4v*)(VT + ((size_t)(b * HDIM + d)) * S_LEN + s) = o;
  }
}

// ---------------------------------------------------------------------------
// elementwise split f32 -> (hi, lo) bf16; 4 elements/thread
// ---------------------------------------------------------------------------
__global__ __launch_bounds__(256) void split_f32_kernel(
    const float* __restrict__ src, short* __restrict__ hi,
    short* __restrict__ lo) {
  size_t idx = (size_t)blockIdx.x * 256 + threadIdx.x;
  float4 v = *(const float4*)(src + idx * 4);
  float vv[4] = {v.x, v.y, v.z, v.w};
  short4v h4, l4;
#pragma unroll
  for (int j = 0; j < 4; ++j) {
    short h = f2bf(vv[j]);
    h4[j] = h;
    l4[j] = f2bf(vv[j] - bf2f(h));
  }
  *(short4v*)(hi + idx * 4) = h4;
  *(short4v*)(lo + idx * 4) = l4;
}

// ---------------------------------------------------------------------------
// tiled transpose + (optional split) f32 W[K][N] -> bf16 T[N][K]
// grid (N/64, K/64), 256 threads
// ---------------------------------------------------------------------------
template <bool SPLIT>
__global__ __launch_bounds__(256) void transpose_split_kernel(
    const float* __restrict__ W, short* __restrict__ Th,
    short* __restrict__ Tl, int K, int N) {
  __shared__ float T[64][65];
  const int tid = threadIdx.x;
  const int k0 = blockIdx.y * 64, n0 = blockIdx.x * 64;
  {
    int r = tid >> 2, c0 = (tid & 3) * 16;
    const float* src = W + (size_t)(k0 + r) * N + n0 + c0;
#pragma unroll
    for (int j = 0; j < 4; ++j) {
      float4 v = *(const float4*)(src + 4 * j);
      T[r][c0 + 4 * j + 0] = v.x; T[r][c0 + 4 * j + 1] = v.y;
      T[r][c0 + 4 * j + 2] = v.z; T[r][c0 + 4 * j + 3] = v.w;
    }
  }
  __syncthreads();
  {
    int n = tid >> 2, kc = (tid & 3) * 16;
    short8 h0, h1, l0, l1;
#pragma unroll
    for (int i = 0; i < 8; ++i) {
      float a = T[kc + i][n];
      float b = T[kc + 8 + i][n];
      short ha = f2bf(a), hb = f2bf(b);
      h0[i] = ha; h1[i] = hb;
      if (SPLIT) { l0[i] = f2bf(a - bf2f(ha)); l1[i] = f2bf(b - bf2f(hb)); }
    }
    size_t off = (size_t)(n0 + n) * K + k0 + kc;
    *(short8*)(Th + off) = h0;
    *(short8*)(Th + off + 8) = h1;
    if (SPLIT) {
      *(short8*)(Tl + off) = l0;
      *(short8*)(Tl + off + 8) = l1;
    }
  }
}

// ---------------------------------------------------------------------------
// MFMA GEMM: C[M][N] = A[M][K] @ B[K][N], with Bt = B^T given as [N][K] bf16.
// SPLIT=true : A,Bt given as (hi,lo) pairs, 3-term product, epilogue stores
//              split bf16 (Chi, Clo).
// SPLIT=false: plain bf16 inputs, epilogue stores f32 C.
// 128x128 tile, BK=32, 256 threads = 4 waves; wave w: rows w*32..w*32+31,
// all 128 cols. 16x16x32 bf16 MFMA. Staging via global_load_lds width 16.
// ---------------------------------------------------------------------------
template <bool SPLIT>
__global__ __launch_bounds__(256, 2) void gemm_mfma(
    const short* __restrict__ Ah, const short* __restrict__ Al,
    const short* __restrict__ Bth, const short* __restrict__ Btl,
    float* __restrict__ C, short* __restrict__ Chi, short* __restrict__ Clo,
    int M, int N, int K) {
  extern __shared__ short sm[];
  short* AhS = sm;            // [128][32]
  short* BhS = sm + 4096;     // [128][32]
  short* AlS = sm + 8192;     // (SPLIT only)
  short* BlS = sm + 12288;

  const int tid  = threadIdx.x;
  const int w    = tid >> 6;
  const int lane = tid & 63;
  const int quad = lane >> 4, col16 = lane & 15;
  const int row0 = blockIdx.y * 128, col0 = blockIdx.x * 128;

  // staging: wave w covers rows w*32 .. w*32+31 (two 16-row instructions)
  const int srow  = w * 32 + (lane >> 2);
  const int kpart = (lane & 3) * 8;
  const short* pAh0 = Ah + (size_t)(row0 + srow) * K + kpart;
  const short* pAh1 = pAh0 + (size_t)16 * K;
  const short* pBh0 = Bth + (size_t)(col0 + srow) * K + kpart;
  const short* pBh1 = pBh0 + (size_t)16 * K;
  const short* pAl0 = SPLIT ? Al + (size_t)(row0 + srow) * K + kpart : nullptr;
  const short* pAl1 = SPLIT ? pAl0 + (size_t)16 * K : nullptr;
  const short* pBl0 = SPLIT ? Btl + (size_t)(col0 + srow) * K + kpart : nullptr;
  const short* pBl1 = SPLIT ? pBl0 + (size_t)16 * K : nullptr;
  short* lA0 = AhS + (w * 32) * 32;          // wave-uniform LDS bases
  short* lA1 = AhS + (w * 32 + 16) * 32;
  short* lB0 = BhS + (w * 32) * 32;
  short* lB1 = BhS + (w * 32 + 16) * 32;

  f32x4 acc[2][8];
#pragma unroll
  for (int mt = 0; mt < 2; ++mt)
#pragma unroll
    for (int nt = 0; nt < 8; ++nt) {
      acc[mt][nt][0] = 0.f; acc[mt][nt][1] = 0.f;
      acc[mt][nt][2] = 0.f; acc[mt][nt][3] = 0.f;
    }

  const int nchunk = K >> 5;
  for (int c = 0; c < nchunk; ++c) {
    glds16(pAh0, lA0); glds16(pAh1, lA1);
    glds16(pBh0, lB0); glds16(pBh1, lB1);
    if constexpr (SPLIT) {
      glds16(pAl0, AlS + (w * 32) * 32);
      glds16(pAl1, AlS + (w * 32 + 16) * 32);
      glds16(pBl0, BlS + (w * 32) * 32);
      glds16(pBl1, BlS + (w * 32 + 16) * 32);
    }
    pAh0 += 32; pAh1 += 32; pBh0 += 32; pBh1 += 32;
    if constexpr (SPLIT) { pAl0 += 32; pAl1 += 32; pBl0 += 32; pBl1 += 32; }
    __syncthreads();   // drains glds (compiler emits vmcnt(0) before barrier)

    short8 afh[2], afl[2];
#pragma unroll
    for (int mt = 0; mt < 2; ++mt) {
      afh[mt] = *(const short8*)&AhS[(w * 32 + mt * 16 + col16) * 32 + quad * 8];
      if constexpr (SPLIT)
        afl[mt] = *(const short8*)&AlS[(w * 32 + mt * 16 + col16) * 32 + quad * 8];
    }
#pragma unroll
    for (int nt = 0; nt < 8; ++nt) {
      short8 bh = *(const short8*)&BhS[(nt * 16 + col16) * 32 + quad * 8];
      if constexpr (SPLIT) {
        short8 bl = *(const short8*)&BlS[(nt * 16 + col16) * 32 + quad * 8];
#pragma unroll
        for (int mt = 0; mt < 2; ++mt) {
          acc[mt][nt] = __builtin_amdgcn_mfma_f32_16x16x32_bf16(afh[mt], bh, acc[mt][nt], 0, 0, 0);
          acc[mt][nt] = __builtin_amdgcn_mfma_f32_16x16x32_bf16(afl[mt], bh, acc[mt][nt], 0, 0, 0);
          acc[mt][nt] = __builtin_amdgcn_mfma_f32_16x16x32_bf16(afh[mt], bl, acc[mt][nt], 0, 0, 0);
        }
      } else {
#pragma unroll
        for (int mt = 0; mt < 2; ++mt)
          acc[mt][nt] = __builtin_amdgcn_mfma_f32_16x16x32_bf16(afh[mt], bh, acc[mt][nt], 0, 0, 0);
      }
    }
    __syncthreads();   // all reads done before next chunk's staging
  }

  // epilogue: C layout row=quad*4+r, col=lane&15 within each 16x16 tile
#pragma unroll
  for (int mt = 0; mt < 2; ++mt)
#pragma unroll
    for (int nt = 0; nt < 8; ++nt)
#pragma unroll
      for (int r = 0; r < 4; ++r) {
        int row = row0 + w * 32 + mt * 16 + quad * 4 + r;
        int col = col0 + nt * 16 + col16;
        float v = acc[mt][nt][r];
        if constexpr (SPLIT) {
          short h = f2bf(v);
          size_t off = (size_t)row * N + col;
          Chi[off] = h;
          Clo[off] = f2bf(v - bf2f(h));
        } else {
          C[(size_t)row * N + col] = v;
        }
      }
}

// ---------------------------------------------------------------------------
// MFMA flash attention (unchanged except bf16 AO epilogue).
// ---------------------------------------------------------------------------
#define LDK 136
#define LDV 80
#define LDP 72

__global__ __launch_bounds__(256, 2) void flash_mfma(
    const short* __restrict__ Qh, const short* __restrict__ Ql,
    const short* __restrict__ Kh, const short* __restrict__ Kl,
    const short* __restrict__ VT, const float* __restrict__ mask,
    short* __restrict__ AO) {
  __shared__ short KhS[64 * LDK];
  __shared__ short KlS[64 * LDK];
  __shared__ short VtS[128 * LDV];
  __shared__ short PsS[4][16 * LDP];

  const int tid   = threadIdx.x;
  const int w     = tid >> 6;
  const int lane  = tid & 63;
  const int quad  = lane >> 4;
  const int col16 = lane & 15;
  const int bh = blockIdx.y, b = bh >> 4, h = bh & 15;
  const int t0 = blockIdx.x * 64;

  {
    int r = tid >> 2, c0 = (tid & 3) * 32;
    const short* qh = Qh + (size_t)(b * S_LEN + t0 + r) * EMB + h * HDIM + c0;
    const short* ql = Ql + (size_t)(b * S_LEN + t0 + r) * EMB + h * HDIM + c0;
#pragma unroll
    for (int j = 0; j < 4; ++j) {
      *(short8*)&KhS[r * LDK + c0 + 8 * j] = *(const short8*)(qh + 8 * j);
      *(short8*)&KlS[r * LDK + c0 + 8 * j] = *(const short8*)(ql + 8 * j);
    }
  }
  __syncthreads();
  short8 qfh[4], qfl[4];
#pragma unroll
  for (int c = 0; c < 4; ++c) {
    qfh[c] = *(const short8*)&KhS[(16 * w + col16) * LDK + c * 32 + quad * 8];
    qfl[c] = *(const short8*)&KlS[(16 * w + col16) * LDK + c * 32 + quad * 8];
  }

  f32x4 oacc[8];
#pragma unroll
  for (int d = 0; d < 8; ++d) { oacc[d][0] = 0.f; oacc[d][1] = 0.f; oacc[d][2] = 0.f; oacc[d][3] = 0.f; }
  float mrow[4] = {-3.0e38f, -3.0e38f, -3.0e38f, -3.0e38f};
  float lrow[4] = {0.f, 0.f, 0.f, 0.f};

  for (int s0 = 0; s0 < S_LEN; s0 += 64) {
    __syncthreads();
    {
      int r = tid >> 2, c0 = (tid & 3) * 32;
      const short* kh = Kh + (size_t)(b * S_LEN + s0 + r) * HDIM + c0;
      const short* kl = Kl + (size_t)(b * S_LEN + s0 + r) * HDIM + c0;
#pragma unroll
      for (int j = 0; j < 4; ++j) {
        *(short8*)&KhS[r * LDK + c0 + 8 * j] = *(const short8*)(kh + 8 * j);
        *(short8*)&KlS[r * LDK + c0 + 8 * j] = *(const short8*)(kl + 8 * j);
      }
      int d = tid >> 1, c1 = (tid & 1) * 32;
      const short* vt = VT + (size_t)(b * HDIM + d) * S_LEN + s0 + c1;
#pragma unroll
      for (int j = 0; j < 4; ++j)
        *(short8*)&VtS[d * LDV + c1 + 8 * j] = *(const short8*)(vt + 8 * j);
    }
    float mreg[4][4];
    {
      const float* mp = mask + (size_t)b * S_LEN * S_LEN
                      + (size_t)(t0 + 16 * w + quad * 4) * S_LEN + s0 + col16;
#pragma unroll
      for (int r = 0; r < 4; ++r)
#pragma unroll
        for (int nt = 0; nt < 4; ++nt)
          mreg[r][nt] = mp[(size_t)r * S_LEN + nt * 16];
    }
    __syncthreads();

    f32x4 sacc[4];
#pragma unroll
    for (int nt = 0; nt < 4; ++nt) { sacc[nt][0] = 0.f; sacc[nt][1] = 0.f; sacc[nt][2] = 0.f; sacc[nt][3] = 0.f; }
#pragma unroll
    for (int c = 0; c < 4; ++c) {
#pragma unroll
      for (int nt = 0; nt < 4; ++nt) {
        short8 kh8 = *(const short8*)&KhS[(nt * 16 + col16) * LDK + c * 32 + quad * 8];
        short8 kl8 = *(const short8*)&KlS[(nt * 16 + col16) * LDK + c * 32 + quad * 8];
        sacc[nt] = __builtin_amdgcn_mfma_f32_16x16x32_bf16(qfh[c], kh8, sacc[nt], 0, 0, 0);
        sacc[nt] = __builtin_amdgcn_mfma_f32_16x16x32_bf16(qfl[c], kh8, sacc[nt], 0, 0, 0);
        sacc[nt] = __builtin_amdgcn_mfma_f32_16x16x32_bf16(qfh[c], kl8, sacc[nt], 0, 0, 0);
      }
    }

    float alr[4];
#pragma unroll
    for (int r = 0; r < 4; ++r) {
      float v0 = sacc[0][r] + mreg[r][0];
      float v1 = sacc[1][r] + mreg[r][1];
      float v2 = sacc[2][r] + mreg[r][2];
      float v3 = sacc[3][r] + mreg[r][3];
      float mx = fmaxf(fmaxf(v0, v1), fmaxf(v2, v3));
      mx = fmaxf(mx, __shfl_xor(mx, 1));
      mx = fmaxf(mx, __shfl_xor(mx, 2));
      mx = fmaxf(mx, __shfl_xor(mx, 4));
      mx = fmaxf(mx, __shfl_xor(mx, 8));
      float nm = fmaxf(mrow[r], mx);
      short p0 = f2bf(__expf(v0 - nm));
      short p1 = f2bf(__expf(v1 - nm));
      short p2 = f2bf(__expf(v2 - nm));
      short p3 = f2bf(__expf(v3 - nm));
      float ps = (bf2f(p0) + bf2f(p1)) + (bf2f(p2) + bf2f(p3));
      ps += __shfl_xor(ps, 1);
      ps += __shfl_xor(ps, 2);
      ps += __shfl_xor(ps, 4);
      ps += __shfl_xor(ps, 8);
      float al = __expf(mrow[r] - nm);
      lrow[r] = lrow[r] * al + ps;
      mrow[r] = nm;
      alr[r] = al;
      int pbase = (quad * 4 + r) * LDP + col16;
      PsS[w][pbase + 0]  = p0;
      PsS[w][pbase + 16] = p1;
      PsS[w][pbase + 32] = p2;
      PsS[w][pbase + 48] = p3;
    }
#pragma unroll
    for (int d = 0; d < 8; ++d)
#pragma unroll
      for (int r = 0; r < 4; ++r) oacc[d][r] *= alr[r];

    __asm__ volatile("s_waitcnt lgkmcnt(0)" ::: "memory");

    short8 pa0 = *(const short8*)&PsS[w][col16 * LDP + quad * 8];
    short8 pa1 = *(const short8*)&PsS[w][col16 * LDP + 32 + quad * 8];
#pragma unroll
    for (int d = 0; d < 8; ++d) {
      const short* vb = &VtS[(d * 16 + col16) * LDV + quad * 8];
      short8 vb0 = *(const short8*)(vb);
      short8 vb1 = *(const short8*)(vb + 32);
      oacc[d] = __builtin_amdgcn_mfma_f32_16x16x32_bf16(pa0, vb0, oacc[d], 0, 0, 0);
      oacc[d] = __builtin_amdgcn_mfma_f32_16x16x32_bf16(pa1, vb1, oacc[d], 0, 0, 0);
    }
  }

  // epilogue: normalize rows, store bf16 AO
#pragma unroll
  for (int r = 0; r < 4; ++r) {
    float inv = 1.0f / lrow[r];
    short* dst = AO + (size_t)(b * S_LEN + t0 + 16 * w + quad * 4 + r) * EMB
               + h * HDIM + col16;
#pragma unroll
    for (int d = 0; d < 8; ++d) dst[d * 16] = f2bf(oacc[d][r] * inv);
  }
}

// ---------------------------------------------------------------------------
extern "C" void kernel_launch(void* const* d_in, const int* in_sizes, int n_in,
                              void* d_out, int out_size, void* d_ws, size_t ws_size,
                              hipStream_t stream) {
  const float* x    = (const float*)d_in[0];
  const float* mask = (const float*)d_in[1];
  const float* W1   = (const float*)d_in[2];
  const float* W2   = (const float*)d_in[3];
  const float* W3   = (const float*)d_in[4];
  float* out = (float*)d_out;

  char* ws = (char*)d_ws;
  size_t off = 0;
  float* KV   = (float*)(ws + off); off += (size_t)4096 * 256 * 4;      //  4 MiB
  float* Wkv  = (float*)(ws + off); off += (size_t)2048 * 256 * 4;      //  2 MiB
  short* AObf = (short*)(ws + off); off += (size_t)4096 * 2048 * 2;     // 16 MiB
  short* Qh   = (short*)(ws + off); off += (size_t)4096 * 2048 * 2;     // 16 MiB
  short* Ql   = (short*)(ws + off); off += (size_t)4096 * 2048 * 2;     // 16 MiB
  short* Khb  = (short*)(ws + off); off += (size_t)4096 * 128 * 2;      //  1 MiB
  short* Klb  = (short*)(ws + off); off += (size_t)4096 * 128 * 2;      //  1 MiB
  short* VT   = (short*)(ws + off); off += (size_t)2 * 128 * 2048 * 2;  //  1 MiB
  short* xh   = (short*)(ws + off); off += (size_t)4096 * 2048 * 2;     // 16 MiB
  short* xl   = (short*)(ws + off); off += (size_t)4096 * 2048 * 2;     // 16 MiB
  short* W2th = (short*)(ws + off); off += (size_t)2048 * 2048 * 2;     //  8 MiB
  short* W2tl = (short*)(ws + off); off += (size_t)2048 * 2048 * 2;     //  8 MiB
  short* W3t  = (short*)xh;  // alias: xh dead after Q-GEMM, W3t built after

  const int M = 2 * S_LEN;  // 4096

  // KV path (fp32 logit-accurate K)
  reduce_w1_kernel<<<2048, 256, 0, stream>>>(W1, Wkv);
  gemm_f32<<<dim3(256 / 64, M / 64), 256, 0, stream>>>(x, Wkv, KV, M, 256, EMB);
  split_kv_kernel<<<1024, 256, 0, stream>>>(KV, Khb, Klb, VT);

  // Q path: split x and W2^T, split-bf16 MFMA GEMM -> Qh/Ql
  split_f32_kernel<<<8192, 256, 0, stream>>>(x, xh, xl);
  transpose_split_kernel<true><<<dim3(32, 32), 256, 0, stream>>>(W2, W2th, W2tl, EMB, EMB);
  gemm_mfma<true><<<dim3(EMB / 128, M / 128), 256, 32768, stream>>>(
      xh, xl, W2th, W2tl, nullptr, Qh, Ql, M, EMB, EMB);

  // attention
  flash_mfma<<<dim3(S_LEN / 64, 2 * NHEAD), 256, 0, stream>>>(
      Qh, Ql, Khb, Klb, VT, mask, AObf);

  // output projection: plain bf16 MFMA GEMM
  transpose_split_kernel<false><<<dim3(32, 32), 256, 0, stream>>>(W3, W3t, nullptr, EMB, EMB);
  gemm_mfma<false><<<dim3(EMB / 128, M / 128), 256, 16384, stream>>>(
      AObf, nullptr, W3t, nullptr, out, nullptr, nullptr, M, EMB, EMB);
}

// Round 4
// 577.092 us; speedup vs baseline: 6.0323x; 1.1362x over previous
//
#include <hip/hip_runtime.h>
#include <cstdint>

#define S_LEN 2048
#define EMB   2048
#define NHEAD 16
#define HDIM  128
#define NFUSE 2304   // fused proj width: 2048 q | 128 k | 128 v
#define LOG2E 1.4426950408889634f

typedef __attribute__((ext_vector_type(8))) short short8;
typedef __attribute__((ext_vector_type(4))) short short4v;
typedef __attribute__((ext_vector_type(4))) float f32x4;
typedef unsigned int u32;

// round-to-nearest-even float -> bf16 (finite inputs)
__device__ inline short f2bf(float x) {
  union { float f; uint32_t u; } v; v.f = x;
  uint32_t r = v.u + 0x7fffu + ((v.u >> 16) & 1u);
  return (short)(r >> 16);
}
__device__ inline float bf2f(short b) {
  union { uint32_t u; float f; } v; v.u = ((uint32_t)(uint16_t)b) << 16;
  return v.f;
}
// raw v_exp_f32 (2^x); inputs are pre-scaled to log2 domain
__device__ inline float fexp2(float x) {
  float r;
  __asm__ volatile("v_exp_f32 %0, %1" : "=v"(r) : "v"(x));
  return r;
}
// async global->LDS, 16B per lane; lds base must be wave-uniform
__device__ inline void glds16(const short* g, short* l) {
  __builtin_amdgcn_global_load_lds(
      (const __attribute__((address_space(1))) u32*)g,
      (__attribute__((address_space(3))) u32*)l, 16, 0, 0);
}

// ---------------------------------------------------------------------------
// W1 group-reduce -> Wkv f32 [2048][256] (k cols 0..127, v cols 128..255)
// ---------------------------------------------------------------------------
__global__ __launch_bounds__(256) void reduce_w1_kernel(
    const float* __restrict__ W1, float* __restrict__ Wkv) {
  int idx = blockIdx.x * 256 + threadIdx.x;
  int i = idx >> 8;
  int c = idx & 255;
  int base = (c < 128) ? c : (c + 384);
  const float* r = W1 + (size_t)i * 1024 + base;
  Wkv[idx] = (r[0] + r[128]) + (r[256] + r[384]);
}

// ---------------------------------------------------------------------------
// elementwise split f32 -> (hi, lo) bf16; 4 elements/thread
// ---------------------------------------------------------------------------
__global__ __launch_bounds__(256) void split_f32_kernel(
    const float* __restrict__ src, short* __restrict__ hi,
    short* __restrict__ lo) {
  size_t idx = (size_t)blockIdx.x * 256 + threadIdx.x;
  float4 v = *(const float4*)(src + idx * 4);
  float vv[4] = {v.x, v.y, v.z, v.w};
  short4v h4, l4;
#pragma unroll
  for (int j = 0; j < 4; ++j) {
    short h = f2bf(vv[j]);
    h4[j] = h;
    l4[j] = f2bf(vv[j] - bf2f(h));
  }
  *(short4v*)(hi + idx * 4) = h4;
  *(short4v*)(lo + idx * 4) = l4;
}

// ---------------------------------------------------------------------------
// tiled transpose + (optional split) f32 W[K][N] -> bf16 T[N][K]
// grid (N/64, K/64), 256 threads
// ---------------------------------------------------------------------------
template <bool SPLIT>
__global__ __launch_bounds__(256) void transpose_split_kernel(
    const float* __restrict__ W, short* __restrict__ Th,
    short* __restrict__ Tl, int K, int N) {
  __shared__ float T[64][65];
  const int tid = threadIdx.x;
  const int k0 = blockIdx.y * 64, n0 = blockIdx.x * 64;
  {
    int r = tid >> 2, c0 = (tid & 3) * 16;
    const float* src = W + (size_t)(k0 + r) * N + n0 + c0;
#pragma unroll
    for (int j = 0; j < 4; ++j) {
      float4 v = *(const float4*)(src + 4 * j);
      T[r][c0 + 4 * j + 0] = v.x; T[r][c0 + 4 * j + 1] = v.y;
      T[r][c0 + 4 * j + 2] = v.z; T[r][c0 + 4 * j + 3] = v.w;
    }
  }
  __syncthreads();
  {
    int n = tid >> 2, kc = (tid & 3) * 16;
    short8 h0, h1, l0, l1;
#pragma unroll
    for (int i = 0; i < 8; ++i) {
      float a = T[kc + i][n];
      float b = T[kc + 8 + i][n];
      short ha = f2bf(a), hb = f2bf(b);
      h0[i] = ha; h1[i] = hb;
      if (SPLIT) { l0[i] = f2bf(a - bf2f(ha)); l1[i] = f2bf(b - bf2f(hb)); }
    }
    size_t off = (size_t)(n0 + n) * K + k0 + kc;
    *(short8*)(Th + off) = h0;
    *(short8*)(Th + off + 8) = h1;
    if (SPLIT) {
      *(short8*)(Tl + off) = l0;
      *(short8*)(Tl + off + 8) = l1;
    }
  }
}

// ---------------------------------------------------------------------------
// MFMA GEMM: C[M][N] = A[M][K] @ B (Bt = B^T as [N][K] bf16).
// SPLIT: 3-term split-bf16 product, epilogue stores split bf16 (Chi,Clo),
//        scaled by log2e for cols < qlim (the Q columns).
// !SPLIT: plain bf16, f32 C out.
// 128x128 tile, BK=32, 4 waves; global_load_lds width-16 staging.
// ---------------------------------------------------------------------------
template <bool SPLIT>
__global__ __launch_bounds__(256, 2) void gemm_mfma(
    const short* __restrict__ Ah, const short* __restrict__ Al,
    const short* __restrict__ Bth, const short* __restrict__ Btl,
    float* __restrict__ C, short* __restrict__ Chi, short* __restrict__ Clo,
    int M, int N, int K, int qlim) {
  extern __shared__ short sm[];
  short* AhS = sm;            // [128][32]
  short* BhS = sm + 4096;
  short* AlS = sm + 8192;     // (SPLIT only)
  short* BlS = sm + 12288;

  const int tid  = threadIdx.x;
  const int w    = tid >> 6;
  const int lane = tid & 63;
  const int quad = lane >> 4, col16 = lane & 15;
  const int row0 = blockIdx.y * 128, col0 = blockIdx.x * 128;
  const float esc = (col0 < qlim) ? LOG2E : 1.0f;

  const int srow  = w * 32 + (lane >> 2);
  const int kpart = (lane & 3) * 8;
  const short* pAh0 = Ah + (size_t)(row0 + srow) * K + kpart;
  const short* pAh1 = pAh0 + (size_t)16 * K;
  const short* pBh0 = Bth + (size_t)(col0 + srow) * K + kpart;
  const short* pBh1 = pBh0 + (size_t)16 * K;
  const short* pAl0 = SPLIT ? Al + (size_t)(row0 + srow) * K + kpart : nullptr;
  const short* pAl1 = SPLIT ? pAl0 + (size_t)16 * K : nullptr;
  const short* pBl0 = SPLIT ? Btl + (size_t)(col0 + srow) * K + kpart : nullptr;
  const short* pBl1 = SPLIT ? pBl0 + (size_t)16 * K : nullptr;
  short* lA0 = AhS + (w * 32) * 32;
  short* lA1 = AhS + (w * 32 + 16) * 32;
  short* lB0 = BhS + (w * 32) * 32;
  short* lB1 = BhS + (w * 32 + 16) * 32;

  f32x4 acc[2][8];
#pragma unroll
  for (int mt = 0; mt < 2; ++mt)
#pragma unroll
    for (int nt = 0; nt < 8; ++nt) {
      acc[mt][nt][0] = 0.f; acc[mt][nt][1] = 0.f;
      acc[mt][nt][2] = 0.f; acc[mt][nt][3] = 0.f;
    }

  const int nchunk = K >> 5;
  for (int c = 0; c < nchunk; ++c) {
    glds16(pAh0, lA0); glds16(pAh1, lA1);
    glds16(pBh0, lB0); glds16(pBh1, lB1);
    if constexpr (SPLIT) {
      glds16(pAl0, AlS + (w * 32) * 32);
      glds16(pAl1, AlS + (w * 32 + 16) * 32);
      glds16(pBl0, BlS + (w * 32) * 32);
      glds16(pBl1, BlS + (w * 32 + 16) * 32);
    }
    pAh0 += 32; pAh1 += 32; pBh0 += 32; pBh1 += 32;
    if constexpr (SPLIT) { pAl0 += 32; pAl1 += 32; pBl0 += 32; pBl1 += 32; }
    __syncthreads();

    short8 afh[2], afl[2];
#pragma unroll
    for (int mt = 0; mt < 2; ++mt) {
      afh[mt] = *(const short8*)&AhS[(w * 32 + mt * 16 + col16) * 32 + quad * 8];
      if constexpr (SPLIT)
        afl[mt] = *(const short8*)&AlS[(w * 32 + mt * 16 + col16) * 32 + quad * 8];
    }
#pragma unroll
    for (int nt = 0; nt < 8; ++nt) {
      short8 bh = *(const short8*)&BhS[(nt * 16 + col16) * 32 + quad * 8];
      if constexpr (SPLIT) {
        short8 bl = *(const short8*)&BlS[(nt * 16 + col16) * 32 + quad * 8];
#pragma unroll
        for (int mt = 0; mt < 2; ++mt) {
          acc[mt][nt] = __builtin_amdgcn_mfma_f32_16x16x32_bf16(afh[mt], bh, acc[mt][nt], 0, 0, 0);
          acc[mt][nt] = __builtin_amdgcn_mfma_f32_16x16x32_bf16(afl[mt], bh, acc[mt][nt], 0, 0, 0);
          acc[mt][nt] = __builtin_amdgcn_mfma_f32_16x16x32_bf16(afh[mt], bl, acc[mt][nt], 0, 0, 0);
        }
      } else {
#pragma unroll
        for (int mt = 0; mt < 2; ++mt)
          acc[mt][nt] = __builtin_amdgcn_mfma_f32_16x16x32_bf16(afh[mt], bh, acc[mt][nt], 0, 0, 0);
      }
    }
    __syncthreads();
  }

#pragma unroll
  for (int mt = 0; mt < 2; ++mt)
#pragma unroll
    for (int nt = 0; nt < 8; ++nt)
#pragma unroll
      for (int r = 0; r < 4; ++r) {
        int row = row0 + w * 32 + mt * 16 + quad * 4 + r;
        int col = col0 + nt * 16 + col16;
        float v = acc[mt][nt][r];
        if constexpr (SPLIT) {
          v *= esc;
          short h = f2bf(v);
          size_t off = (size_t)row * N + col;
          Chi[off] = h;
          Clo[off] = f2bf(v - bf2f(h));
        } else {
          C[(size_t)row * N + col] = v;
        }
      }
}

// ---------------------------------------------------------------------------
// build VT bf16 [2][128][2048] from fused proj output cols 2176..2303 (v-hi)
// grid 64 blocks x 256 thr; block = 64 s-rows
// ---------------------------------------------------------------------------
__global__ __launch_bounds__(256) void build_vt(
    const short* __restrict__ QKh, short* __restrict__ VT) {
  __shared__ short T[64][136];
  const int tid = threadIdx.x;
  const int gs = blockIdx.x * 64;
  const int b = gs >> 11;
  const int s = gs & 2047;
  {
    int r = tid >> 2, c0 = (tid & 3) * 32;
    const short* src = QKh + (size_t)(gs + r) * NFUSE + 2176 + c0;
#pragma unroll
    for (int j = 0; j < 4; ++j)
      *(short8*)&T[r][c0 + 8 * j] = *(const short8*)(src + 8 * j);
  }
  __syncthreads();
  {
    int d = tid >> 1, c = (tid & 1) * 32;
    short* dst = VT + (size_t)(b * HDIM + d) * S_LEN + s + c;
#pragma unroll
    for (int jo = 0; jo < 4; ++jo) {
      short8 o;
#pragma unroll
      for (int i = 0; i < 8; ++i) o[i] = T[c + jo * 8 + i][d];
      *(short8*)(dst + jo * 8) = o;
    }
  }
}

// ---------------------------------------------------------------------------
// MFMA flash attention, BM=128 (2 Q-tiles per wave), BN=64.
// Q/K read from fused proj buffers (row stride NFUSE; K at col 2048).
// Logits arrive in log2 domain (Q pre-scaled by log2e); mask scaled at load.
// grid (S/128, B*H), 256 threads = 4 waves.
// ---------------------------------------------------------------------------
#define LDK 136
#define LDV 72
#define LDP 72

__global__ __launch_bounds__(256, 2) void flash_mfma(
    const short* __restrict__ QKh, const short* __restrict__ QKl,
    const short* __restrict__ VT, const float* __restrict__ mask,
    short* __restrict__ AO) {
  __shared__ short KhS[64 * LDK];
  __shared__ short KlS[64 * LDK];
  __shared__ short VtS[128 * LDV];
  __shared__ short PsS[4][16 * LDP];

  const int tid   = threadIdx.x;
  const int w     = tid >> 6;
  const int lane  = tid & 63;
  const int quad  = lane >> 4;
  const int col16 = lane & 15;
  const int bh = blockIdx.y, b = bh >> 4, h = bh & 15;
  const int t0 = blockIdx.x * 128;

  // ---- stage both Q tiles through LDS, extract A-fragments
  short8 qfh[2][4], qfl[2][4];
#pragma unroll
  for (int t = 0; t < 2; ++t) {
    int r = tid >> 2, c0 = (tid & 3) * 32;
    const short* qh = QKh + (size_t)(b * S_LEN + t0 + t * 64 + r) * NFUSE + h * HDIM + c0;
    const short* ql = QKl + (size_t)(b * S_LEN + t0 + t * 64 + r) * NFUSE + h * HDIM + c0;
#pragma unroll
    for (int j = 0; j < 4; ++j) {
      *(short8*)&KhS[r * LDK + c0 + 8 * j] = *(const short8*)(qh + 8 * j);
      *(short8*)&KlS[r * LDK + c0 + 8 * j] = *(const short8*)(ql + 8 * j);
    }
    __syncthreads();
#pragma unroll
    for (int c = 0; c < 4; ++c) {
      qfh[t][c] = *(const short8*)&KhS[(16 * w + col16) * LDK + c * 32 + quad * 8];
      qfl[t][c] = *(const short8*)&KlS[(16 * w + col16) * LDK + c * 32 + quad * 8];
    }
    __syncthreads();
  }

  f32x4 oacc[2][8];
#pragma unroll
  for (int t = 0; t < 2; ++t)
#pragma unroll
    for (int d = 0; d < 8; ++d) {
      oacc[t][d][0] = 0.f; oacc[t][d][1] = 0.f;
      oacc[t][d][2] = 0.f; oacc[t][d][3] = 0.f;
    }
  float mrow[2][4], lrow[2][4];
#pragma unroll
  for (int t = 0; t < 2; ++t)
#pragma unroll
    for (int r = 0; r < 4; ++r) { mrow[t][r] = -3.0e38f; lrow[t][r] = 0.f; }

  for (int s0 = 0; s0 < S_LEN; s0 += 64) {
    __syncthreads();   // previous iteration's LDS consumers done
    {   // ---- stage K hi/lo [64][128] (from fused buf col 2048) and V^T
      int r = tid >> 2, c0 = (tid & 3) * 32;
      const short* kh = QKh + (size_t)(b * S_LEN + s0 + r) * NFUSE + 2048 + c0;
      const short* kl = QKl + (size_t)(b * S_LEN + s0 + r) * NFUSE + 2048 + c0;
#pragma unroll
      for (int j = 0; j < 4; ++j) {
        *(short8*)&KhS[r * LDK + c0 + 8 * j] = *(const short8*)(kh + 8 * j);
        *(short8*)&KlS[r * LDK + c0 + 8 * j] = *(const short8*)(kl + 8 * j);
      }
      int d = tid >> 1, c1 = (tid & 1) * 32;
      const short* vt = VT + (size_t)(b * HDIM + d) * S_LEN + s0 + c1;
#pragma unroll
      for (int j = 0; j < 4; ++j)
        *(short8*)&VtS[d * LDV + c1 + 8 * j] = *(const short8*)(vt + 8 * j);
    }
    // ---- mask -> registers, scaled into log2 domain
    float mreg[2][4][4];
#pragma unroll
    for (int t = 0; t < 2; ++t) {
      const float* mp = mask + (size_t)b * S_LEN * S_LEN
                      + (size_t)(t0 + t * 64 + 16 * w + quad * 4) * S_LEN + s0 + col16;
#pragma unroll
      for (int r = 0; r < 4; ++r)
#pragma unroll
        for (int nt = 0; nt < 4; ++nt)
          mreg[t][r][nt] = mp[(size_t)r * S_LEN + nt * 16] * LOG2E;
    }
    __syncthreads();

    // ---- QK for both tiles (K fragments read once, used twice)
    f32x4 sacc[2][4];
#pragma unroll
    for (int t = 0; t < 2; ++t)
#pragma unroll
      for (int nt = 0; nt < 4; ++nt) {
        sacc[t][nt][0] = 0.f; sacc[t][nt][1] = 0.f;
        sacc[t][nt][2] = 0.f; sacc[t][nt][3] = 0.f;
      }
#pragma unroll
    for (int c = 0; c < 4; ++c)
#pragma unroll
      for (int nt = 0; nt < 4; ++nt) {
        short8 kh8 = *(const short8*)&KhS[(nt * 16 + col16) * LDK + c * 32 + quad * 8];
        short8 kl8 = *(const short8*)&KlS[(nt * 16 + col16) * LDK + c * 32 + quad * 8];
#pragma unroll
        for (int t = 0; t < 2; ++t) {
          sacc[t][nt] = __builtin_amdgcn_mfma_f32_16x16x32_bf16(qfh[t][c], kh8, sacc[t][nt], 0, 0, 0);
          sacc[t][nt] = __builtin_amdgcn_mfma_f32_16x16x32_bf16(qfl[t][c], kh8, sacc[t][nt], 0, 0, 0);
          sacc[t][nt] = __builtin_amdgcn_mfma_f32_16x16x32_bf16(qfh[t][c], kl8, sacc[t][nt], 0, 0, 0);
        }
      }

    // ---- per tile: online softmax (base-2), P store, rescale, PV
#pragma unroll
    for (int t = 0; t < 2; ++t) {
      float alr[4];
#pragma unroll
      for (int r = 0; r < 4; ++r) {
        float v0 = sacc[t][0][r] + mreg[t][r][0];
        float v1 = sacc[t][1][r] + mreg[t][r][1];
        float v2 = sacc[t][2][r] + mreg[t][r][2];
        float v3 = sacc[t][3][r] + mreg[t][r][3];
        float mx = fmaxf(fmaxf(v0, v1), fmaxf(v2, v3));
        mx = fmaxf(mx, __shfl_xor(mx, 1));
        mx = fmaxf(mx, __shfl_xor(mx, 2));
        mx = fmaxf(mx, __shfl_xor(mx, 4));
        mx = fmaxf(mx, __shfl_xor(mx, 8));
        float nm = fmaxf(mrow[t][r], mx);
        union { float f; u32 u; } p0, p1, p2, p3, q0, q1, q2, q3;
        p0.f = fexp2(v0 - nm);
        p1.f = fexp2(v1 - nm);
        p2.f = fexp2(v2 - nm);
        p3.f = fexp2(v3 - nm);
        // truncate to bf16; sum the truncated values so num/denom cancel
        q0.u = p0.u & 0xffff0000u; q1.u = p1.u & 0xffff0000u;
        q2.u = p2.u & 0xffff0000u; q3.u = p3.u & 0xffff0000u;
        float ps = (q0.f + q1.f) + (q2.f + q3.f);
        ps += __shfl_xor(ps, 1);
        ps += __shfl_xor(ps, 2);
        ps += __shfl_xor(ps, 4);
        ps += __shfl_xor(ps, 8);
        float al = fexp2(mrow[t][r] - nm);
        lrow[t][r] = lrow[t][r] * al + ps;
        mrow[t][r] = nm;
        alr[r] = al;
        int pbase = (quad * 4 + r) * LDP + col16;
        PsS[w][pbase +  0] = (short)(p0.u >> 16);
        PsS[w][pbase + 16] = (short)(p1.u >> 16);
        PsS[w][pbase + 32] = (short)(p2.u >> 16);
        PsS[w][pbase + 48] = (short)(p3.u >> 16);
      }
#pragma unroll
      for (int d = 0; d < 8; ++d)
#pragma unroll
        for (int r = 0; r < 4; ++r) oacc[t][d][r] *= alr[r];

      __asm__ volatile("s_waitcnt lgkmcnt(0)" ::: "memory");  // P visible in-wave

      short8 pa0 = *(const short8*)&PsS[w][col16 * LDP + quad * 8];
      short8 pa1 = *(const short8*)&PsS[w][col16 * LDP + 32 + quad * 8];
#pragma unroll
      for (int d = 0; d < 8; ++d) {
        const short* vb = &VtS[(d * 16 + col16) * LDV + quad * 8];
        short8 vb0 = *(const short8*)(vb);
        short8 vb1 = *(const short8*)(vb + 32);
        oacc[t][d] = __builtin_amdgcn_mfma_f32_16x16x32_bf16(pa0, vb0, oacc[t][d], 0, 0, 0);
        oacc[t][d] = __builtin_amdgcn_mfma_f32_16x16x32_bf16(pa1, vb1, oacc[t][d], 0, 0, 0);
      }
    }
  }

  // ---- epilogue: normalize, store bf16 AO [4096][2048]
#pragma unroll
  for (int t = 0; t < 2; ++t)
#pragma unroll
    for (int r = 0; r < 4; ++r) {
      float inv = 1.0f / lrow[t][r];
      short* dst = AO + (size_t)(b * S_LEN + t0 + t * 64 + 16 * w + quad * 4 + r) * EMB
                 + h * HDIM + col16;
#pragma unroll
      for (int d = 0; d < 8; ++d) dst[d * 16] = f2bf(oacc[t][d][r] * inv);
    }
}

// ---------------------------------------------------------------------------
extern "C" void kernel_launch(void* const* d_in, const int* in_sizes, int n_in,
                              void* d_out, int out_size, void* d_ws, size_t ws_size,
                              hipStream_t stream) {
  const float* x    = (const float*)d_in[0];
  const float* mask = (const float*)d_in[1];
  const float* W1   = (const float*)d_in[2];
  const float* W2   = (const float*)d_in[3];
  const float* W3   = (const float*)d_in[4];
  float* out = (float*)d_out;

  char* ws = (char*)d_ws;
  size_t off = 0;
  short* xh   = (short*)(ws + off); off += (size_t)4096 * 2048 * 2;   // 16 MiB
  short* xl   = (short*)(ws + off); off += (size_t)4096 * 2048 * 2;   // 16 MiB
  short* Wth  = (short*)(ws + off); off += (size_t)NFUSE * 2048 * 2;  //  9 MiB
  short* Wtl  = (short*)(ws + off); off += (size_t)NFUSE * 2048 * 2;  //  9 MiB
  short* QKh  = (short*)(ws + off); off += (size_t)4096 * NFUSE * 2;  // 18 MiB
  short* QKl  = (short*)(ws + off); off += (size_t)4096 * NFUSE * 2;  // 18 MiB
  short* VT   = (short*)(ws + off); off += (size_t)2 * 128 * 2048 * 2;//  1 MiB
  short* AObf = (short*)(ws + off); off += (size_t)4096 * 2048 * 2;   // 16 MiB
  float* Wkv  = (float*)(ws + off); off += (size_t)2048 * 256 * 4;    //  2 MiB
  short* W3t  = xh;  // alias: xh dead after fused GEMM; W3 transpose runs after

  // 1) prep: Wkv reduce, x split, fused W^T split (W2 rows 0..2047, Wkv rows 2048..2303)
  reduce_w1_kernel<<<2048, 256, 0, stream>>>(W1, Wkv);
  split_f32_kernel<<<8192, 256, 0, stream>>>(x, xh, xl);
  transpose_split_kernel<true><<<dim3(32, 32), 256, 0, stream>>>(W2, Wth, Wtl, 2048, 2048);
  transpose_split_kernel<true><<<dim3(4, 32), 256, 0, stream>>>(
      Wkv, Wth + (size_t)2048 * 2048, Wtl + (size_t)2048 * 2048, 2048, 256);

  // 2) fused projection GEMM: [4096][2304] = x @ [W2 | Wk | Wv], split output,
  //    Q cols pre-scaled by log2e
  gemm_mfma<true><<<dim3(NFUSE / 128, 32), 256, 32768, stream>>>(
      xh, xl, Wth, Wtl, nullptr, QKh, QKl, 4096, NFUSE, 2048, 2048);

  // 3) V^T extraction
  build_vt<<<64, 256, 0, stream>>>(QKh, VT);

  // 4) attention
  flash_mfma<<<dim3(S_LEN / 128, 2 * NHEAD), 256, 0, stream>>>(
      QKh, QKl, VT, mask, AObf);

  // 5) output projection (plain bf16)
  transpose_split_kernel<false><<<dim3(32, 32), 256, 0, stream>>>(W3, W3t, nullptr, 2048, 2048);
  gemm_mfma<false><<<dim3(16, 32), 256, 16384, stream>>>(
      AObf, nullptr, W3t, nullptr, out, nullptr, nullptr, 4096, 2048, 2048, 0);
}